// Round 3
// baseline (162.421 us; speedup 1.0000x reference)
//
#include <hip/hip_runtime.h>
#include <hip/hip_bf16.h>
#include <math.h>

// Contrastive (NT-Xent-like) loss over x[16384][64] fp32.
//   x_hat = sqrt(2) * x / ||x||       (sqrt(2)^2 = 2 = 1/T folds temperature)
//   den[j] = sum_i exp(x_hat_i . x_hat_j) - e^2
//   num[j] = exp(x_hat_{j^1} . x_hat_j)
//   out = -log( mean_j num[j] / den[j] )
//
// Round 3: (a) symmetry — only 8256 upper-triangle 128x128 tile pairs, off-diag
// tiles add colsums to den[jb..] AND rowsums to den[ib..] (halves MFMA+exp);
// (b) XOR-swizzled LDS layout chunk = r*8 + (q ^ (r&7)): coalesced staging,
// conflict-free ds_write_b128 AND ds_read_b128 (exactly 8 lanes per 4-bank
// span = b128 phase minimum); (c) 3 dispatches total: den zeroing fused into
// normalize, num extracted from diagonal tiles' accumulators, ratio+log in one
// single-block kernel (round 2 lost ~55 us to 5 dispatches of small kernels).

#define NROWS 16384
#define KDIM 64
#define NTILE 128   // tile rows/cols
#define NTB (NROWS / NTILE)          // 128 tile-blocks per side
#define NPAIRS (NTB * (NTB + 1) / 2) // 8256 upper-triangle tile pairs

typedef __attribute__((ext_vector_type(8))) short short8;   // 8 bf16 = 4 VGPRs
typedef __attribute__((ext_vector_type(4))) float f32x4;

// ---- kernel A: row-normalize + prescale by sqrt(2) -> bf16; zero den ------
__global__ __launch_bounds__(256) void normalize_kernel(const float* __restrict__ x,
                                                        __hip_bfloat16* __restrict__ xnb,
                                                        float* __restrict__ den) {
    const int wave = threadIdx.x >> 6;
    const int lane = threadIdx.x & 63;
    const int row = blockIdx.x * 4 + wave;
    const float v = x[row * KDIM + lane];
    float ss = v * v;
    #pragma unroll
    for (int o = 32; o > 0; o >>= 1) ss += __shfl_xor(ss, o, 64);
    const float inv = 1.41421356237309515f * rsqrtf(fmaxf(ss, 1e-16f));
    xnb[row * KDIM + lane] = __float2bfloat16(v * inv);
    if (blockIdx.x < 64) den[blockIdx.x * 256 + threadIdx.x] = 0.0f;  // den zeroed before den_kernel (stream order)
}

// ---- kernel B: symmetric tile-pair den accumulation -----------------------
// Block = one upper-triangle tile pair (ti<=tj). 4 waves in 2x2; wave tile
// 64x64 via mfma_f32_16x16x32_bf16 (A-frag: lane holds row m=l&15,
// k=(l>>4)*8+e; C/D: col=l&15, row=(l>>4)*4+reg).
// LDS: chunk(r,q) (16B, q = k-bytes/16) stored at index r*8 + (q ^ (r&7)).
__global__ __launch_bounds__(256) void den_kernel(const __hip_bfloat16* __restrict__ xnb,
                                                  float* __restrict__ den,
                                                  float* __restrict__ num) {
    __shared__ float4 As[1024];  // 16 KB: 128 rows x 8 chunks, XOR-swizzled
    __shared__ float4 Bs[1024];

    // triangular decode: blockIdx.x -> (ti, tj), ti <= tj
    const int bt = blockIdx.x;
    int ti = (int)((257.0 - sqrt(66049.0 - 8.0 * (double)bt)) * 0.5);
    while (ti * NTB - ti * (ti - 1) / 2 > bt) ti--;
    while ((ti + 1) * NTB - (ti + 1) * ti / 2 <= bt) ti++;
    const int tj = ti + (bt - (ti * NTB - ti * (ti - 1) / 2));
    const int ib = ti * NTILE, jb = tj * NTILE;
    const bool diag = (ti == tj);

    const int t = threadIdx.x;
    // stage A and B tiles: chunk c -> row r=c>>3, global q=(c&7)^(r&7).
    // Global: 8 lanes cover one 128-B row (q permuted within row) -> coalesced.
    // LDS: lane-consecutive chunks -> 8 distinct rows per 4-bank span = min phases.
    #pragma unroll
    for (int s = 0; s < 4; s++) {
        const int c = s * 256 + t;
        const int r = c >> 3;
        const int q = (c & 7) ^ (r & 7);
        As[c] = *(const float4*)((const char*)xnb + ((size_t)(ib + r) * KDIM + q * 8) * 2);
        Bs[c] = *(const float4*)((const char*)xnb + ((size_t)(jb + r) * KDIM + q * 8) * 2);
    }
    __syncthreads();

    const int lane = t & 63, w = t >> 6;
    const int wi = w >> 1, wj = w & 1;   // 2x2 wave grid, 64x64 per wave
    const int m = lane & 15, p = lane >> 4;

    const f32x4 zero = {0.f, 0.f, 0.f, 0.f};
    f32x4 acc[4][4];
    #pragma unroll
    for (int it = 0; it < 4; it++)
        #pragma unroll
        for (int jt = 0; jt < 4; jt++) acc[it][jt] = zero;

    #pragma unroll
    for (int kc = 0; kc < 2; kc++) {
        short8 af[4], bf[4];
        const int qx = ((kc << 2) | p) ^ (m & 7);   // swizzled chunk slot
        #pragma unroll
        for (int it = 0; it < 4; it++) {
            af[it] = *(const short8*)&As[(wi * 64 + it * 16 + m) * 8 + qx];
            bf[it] = *(const short8*)&Bs[(wj * 64 + it * 16 + m) * 8 + qx];
        }
        #pragma unroll
        for (int it = 0; it < 4; it++)
            #pragma unroll
            for (int jt = 0; jt < 4; jt++)
                acc[it][jt] = __builtin_amdgcn_mfma_f32_16x16x32_bf16(af[it], bf[jt], acc[it][jt], 0, 0, 0);
    }

    // epilogue: exp; column partials (over rows) and row partials (over cols)
    float cs[4] = {0.f, 0.f, 0.f, 0.f};  // per jt: col j = jb + wj*64 + jt*16 + m
    float rs[4][4];                      // per (it,reg): row i = ib + wi*64 + it*16 + p*4 + reg
    #pragma unroll
    for (int it = 0; it < 4; it++) {
        #pragma unroll
        for (int reg = 0; reg < 4; reg++) {
            const float e0 = __expf(acc[it][0][reg]);
            const float e1 = __expf(acc[it][1][reg]);
            const float e2 = __expf(acc[it][2][reg]);
            const float e3 = __expf(acc[it][3][reg]);
            cs[0] += e0; cs[1] += e1; cs[2] += e2; cs[3] += e3;
            rs[it][reg] = (e0 + e1) + (e2 + e3);
        }
    }

    // colsum: reduce over the 4 p-groups; lanes p==0 hold 16 j's each
    #pragma unroll
    for (int jt = 0; jt < 4; jt++) {
        cs[jt] += __shfl_xor(cs[jt], 16, 64);
        cs[jt] += __shfl_xor(cs[jt], 32, 64);
    }
    if (p == 0) {
        #pragma unroll
        for (int jt = 0; jt < 4; jt++)
            atomicAdd(&den[jb + wj * 64 + jt * 16 + m], cs[jt]);
    }

    if (!diag) {
        // rowsum: reduce over the 16 m-lanes; lanes m==0 hold 16 rows each
        #pragma unroll
        for (int it = 0; it < 4; it++)
            #pragma unroll
            for (int reg = 0; reg < 4; reg++) {
                rs[it][reg] += __shfl_xor(rs[it][reg], 1, 64);
                rs[it][reg] += __shfl_xor(rs[it][reg], 2, 64);
                rs[it][reg] += __shfl_xor(rs[it][reg], 4, 64);
                rs[it][reg] += __shfl_xor(rs[it][reg], 8, 64);
            }
        if (m == 0) {
            #pragma unroll
            for (int it = 0; it < 4; it++)
                #pragma unroll
                for (int reg = 0; reg < 4; reg++)
                    atomicAdd(&den[ib + wi * 64 + it * 16 + p * 4 + reg], rs[it][reg]);
        }
    } else if (wi == wj) {
        // num[j] = exp(sim(j^1, j)) from the diagonal tile accumulator.
        // Element (row m^1, col m) of each 16x16 diagonal sub-tile lives in
        // lane (p=(m^1)>>2, m), register (m^1)&3. One unique writer per j.
        const int pc = m ^ 1;
        if ((pc >> 2) == p) {
            #pragma unroll
            for (int it = 0; it < 4; it++)
                num[jb + wj * 64 + it * 16 + m] = __expf(acc[it][it][pc & 3]);
        }
    }
}

// ---- kernel C: out = -log(mean_j num[j]/(den[j]-e^2)), one block ----------
__global__ __launch_bounds__(256) void final_kernel(const float* __restrict__ num,
                                                    const float* __restrict__ den,
                                                    float* __restrict__ out) {
    const float E2 = 7.38905609893065f;  // exp(1/T) = exp(2): diagonal removal
    float s = 0.0f;
    #pragma unroll 4
    for (int i = threadIdx.x; i < NROWS; i += 256)
        s += num[i] / (den[i] - E2);
    #pragma unroll
    for (int o = 32; o > 0; o >>= 1) s += __shfl_xor(s, o, 64);
    __shared__ float ws[4];
    if ((threadIdx.x & 63) == 0) ws[threadIdx.x >> 6] = s;
    __syncthreads();
    if (threadIdx.x == 0)
        out[0] = -logf((ws[0] + ws[1] + ws[2] + ws[3]) / (float)NROWS);
}

extern "C" void kernel_launch(void* const* d_in, const int* in_sizes, int n_in,
                              void* d_out, int out_size, void* d_ws, size_t ws_size,
                              hipStream_t stream) {
    const float* x = (const float*)d_in[0];
    float* out = (float*)d_out;

    // ws layout: xnb [16384*64 bf16 = 2 MB] | den [16384 f32] | num [16384 f32]
    __hip_bfloat16* xnb = (__hip_bfloat16*)d_ws;
    float* den = (float*)((char*)d_ws + (size_t)NROWS * KDIM * sizeof(__hip_bfloat16));
    float* num = den + NROWS;

    normalize_kernel<<<NROWS / 4, 256, 0, stream>>>(x, xnb, den);
    den_kernel<<<NPAIRS, 256, 0, stream>>>(xnb, den, num);
    final_kernel<<<1, 256, 0, stream>>>(num, den, out);
}

// Round 4
// 113.616 us; speedup vs baseline: 1.4296x; 1.4296x over previous
//
#include <hip/hip_runtime.h>
#include <hip/hip_bf16.h>
#include <math.h>

// Contrastive (NT-Xent-like) loss over x[16384][64] fp32.
//   x_hat = sqrt(2) * x / ||x||       (sqrt(2)^2 = 2 = 1/T folds temperature)
//   den[j] = sum_i exp(x_hat_i . x_hat_j) - e^2
//   num[j] = exp(x_hat_{j^1} . x_hat_j)
//   out = -log( mean_j num[j] / den[j] )
//
// Round 4: round 3's 4.2M contended global atomicAdds (WRITE_SIZE 41 MB,
// ~100 us of serialized L2 RMW) replaced by exactly-once scratch stores:
// block (ti<=tj) writes its 128 colsums to S[tj][ti][.] and 128 rowsums to
// S[ti][tj][.] (two coalesced 512B stores), then a 128-block reduce kernel
// streams S, forms den, fuses the num/den ratio + reduction (128 atomics
// total onto one scalar). Single-block final pass eliminated (round 3 lost
// ~tens of us to one CU chasing cold cross-XCD reads).

#define NROWS 16384
#define KDIM 64
#define NTILE 128   // tile rows/cols
#define NTB (NROWS / NTILE)          // 128 tile-blocks per side
#define NPAIRS (NTB * (NTB + 1) / 2) // 8256 upper-triangle tile pairs

typedef __attribute__((ext_vector_type(8))) short short8;   // 8 bf16 = 4 VGPRs
typedef __attribute__((ext_vector_type(4))) float f32x4;

// ---- kernel A: row-normalize + prescale by sqrt(2) -> bf16; zero accum ----
__global__ __launch_bounds__(256) void normalize_kernel(const float* __restrict__ x,
                                                        __hip_bfloat16* __restrict__ xnb,
                                                        float* __restrict__ accum) {
    const int wave = threadIdx.x >> 6;
    const int lane = threadIdx.x & 63;
    const int row = blockIdx.x * 4 + wave;
    const float v = x[row * KDIM + lane];
    float ss = v * v;
    #pragma unroll
    for (int o = 32; o > 0; o >>= 1) ss += __shfl_xor(ss, o, 64);
    const float inv = 1.41421356237309515f * rsqrtf(fmaxf(ss, 1e-16f));
    xnb[row * KDIM + lane] = __float2bfloat16(v * inv);
    if (blockIdx.x == 0 && threadIdx.x == 0) accum[0] = 0.0f;  // used 2 dispatches later
}

// ---- kernel B: symmetric tile-pair partial sums ---------------------------
// Block = one upper-triangle tile pair (ti<=tj). 4 waves in 2x2; wave tile
// 64x64 via mfma_f32_16x16x32_bf16 (A-frag: lane holds row m=l&15,
// k=(l>>4)*8+e; C/D: col=l&15, row=(l>>4)*4+reg).
// LDS: chunk(r,q) (16B, q = k-bytes/16) stored at index r*8 + (q ^ (r&7)):
// coalesced staging, conflict-free ds_write_b128 and ds_read_b128 (r3: 0 conflicts).
__global__ __launch_bounds__(256) void den_kernel(const __hip_bfloat16* __restrict__ xnb,
                                                  float* __restrict__ S,
                                                  float* __restrict__ num) {
    __shared__ float4 As[1024];  // 16 KB: 128 rows x 8 chunks, XOR-swizzled
    __shared__ float4 Bs[1024];
    __shared__ float redc[2][NTILE];  // colsum partials by wi
    __shared__ float redr[2][NTILE];  // rowsum partials by wj

    // triangular decode: blockIdx.x -> (ti, tj), ti <= tj
    const int bt = blockIdx.x;
    int ti = (int)((257.0 - sqrt(66049.0 - 8.0 * (double)bt)) * 0.5);
    while (ti * NTB - ti * (ti - 1) / 2 > bt) ti--;
    while ((ti + 1) * NTB - (ti + 1) * ti / 2 <= bt) ti++;
    const int tj = ti + (bt - (ti * NTB - ti * (ti - 1) / 2));
    const int ib = ti * NTILE, jb = tj * NTILE;
    const bool diag = (ti == tj);

    const int t = threadIdx.x;
    #pragma unroll
    for (int s = 0; s < 4; s++) {
        const int c = s * 256 + t;
        const int r = c >> 3;
        const int q = (c & 7) ^ (r & 7);
        As[c] = *(const float4*)((const char*)xnb + ((size_t)(ib + r) * KDIM + q * 8) * 2);
        Bs[c] = *(const float4*)((const char*)xnb + ((size_t)(jb + r) * KDIM + q * 8) * 2);
    }
    __syncthreads();

    const int lane = t & 63, w = t >> 6;
    const int wi = w >> 1, wj = w & 1;   // 2x2 wave grid, 64x64 per wave
    const int m = lane & 15, p = lane >> 4;

    const f32x4 zero = {0.f, 0.f, 0.f, 0.f};
    f32x4 acc[4][4];
    #pragma unroll
    for (int it = 0; it < 4; it++)
        #pragma unroll
        for (int jt = 0; jt < 4; jt++) acc[it][jt] = zero;

    #pragma unroll
    for (int kc = 0; kc < 2; kc++) {
        short8 af[4], bf[4];
        const int qx = ((kc << 2) | p) ^ (m & 7);   // swizzled chunk slot
        #pragma unroll
        for (int it = 0; it < 4; it++) {
            af[it] = *(const short8*)&As[(wi * 64 + it * 16 + m) * 8 + qx];
            bf[it] = *(const short8*)&Bs[(wj * 64 + it * 16 + m) * 8 + qx];
        }
        #pragma unroll
        for (int it = 0; it < 4; it++)
            #pragma unroll
            for (int jt = 0; jt < 4; jt++)
                acc[it][jt] = __builtin_amdgcn_mfma_f32_16x16x32_bf16(af[it], bf[jt], acc[it][jt], 0, 0, 0);
    }

    // epilogue: exp; column partials (over rows) and row partials (over cols)
    float cs[4] = {0.f, 0.f, 0.f, 0.f};  // per jt: col j = wj*64 + jt*16 + m
    float rs[4][4];                      // per (it,reg): row i = wi*64 + it*16 + p*4 + reg
    #pragma unroll
    for (int it = 0; it < 4; it++) {
        #pragma unroll
        for (int reg = 0; reg < 4; reg++) {
            const float e0 = __expf(acc[it][0][reg]);
            const float e1 = __expf(acc[it][1][reg]);
            const float e2 = __expf(acc[it][2][reg]);
            const float e3 = __expf(acc[it][3][reg]);
            cs[0] += e0; cs[1] += e1; cs[2] += e2; cs[3] += e3;
            rs[it][reg] = (e0 + e1) + (e2 + e3);
        }
    }

    // colsum: reduce over the 4 p-groups; lanes p==0 hold 16 j's each
    #pragma unroll
    for (int jt = 0; jt < 4; jt++) {
        cs[jt] += __shfl_xor(cs[jt], 16, 64);
        cs[jt] += __shfl_xor(cs[jt], 32, 64);
    }
    if (p == 0) {
        #pragma unroll
        for (int jt = 0; jt < 4; jt++)
            redc[wi][wj * 64 + jt * 16 + m] = cs[jt];
    }

    if (!diag) {
        // rowsum: reduce over the 16 m-lanes; lanes m==0 hold 16 rows each
        #pragma unroll
        for (int it = 0; it < 4; it++)
            #pragma unroll
            for (int reg = 0; reg < 4; reg++) {
                rs[it][reg] += __shfl_xor(rs[it][reg], 1, 64);
                rs[it][reg] += __shfl_xor(rs[it][reg], 2, 64);
                rs[it][reg] += __shfl_xor(rs[it][reg], 4, 64);
                rs[it][reg] += __shfl_xor(rs[it][reg], 8, 64);
            }
        if (m == 0) {
            #pragma unroll
            for (int it = 0; it < 4; it++)
                #pragma unroll
                for (int reg = 0; reg < 4; reg++)
                    redr[wj][wi * 64 + it * 16 + p * 4 + reg] = rs[it][reg];
        }
    } else if (wi == wj) {
        // num[j] = exp(sim(j^1, j)) from the diagonal tile accumulator.
        // Element (row m^1, col m) of each 16x16 diagonal sub-tile lives in
        // lane (p=(m^1)>>2, m), register (m^1)&3. One unique writer per j.
        const int pc = m ^ 1;
        if ((pc >> 2) == p) {
            #pragma unroll
            for (int it = 0; it < 4; it++)
                num[jb + wj * 64 + it * 16 + m] = __expf(acc[it][it][pc & 3]);
        }
    }
    __syncthreads();

    // exactly-once coalesced partial stores (no atomics):
    //   colsums -> S[tj][ti][c]   (contribution to den[jb + c])
    //   rowsums -> S[ti][tj][r]   (contribution to den[ib + r], ti<tj only)
    if (t < NTILE) {
        S[((size_t)tj * NTB + ti) * NTILE + t] = redc[0][t] + redc[1][t];
    } else if (!diag) {
        const int u = t - NTILE;
        S[((size_t)ti * NTB + tj) * NTILE + u] = redr[0][u] + redr[1][u];
    }
}

// ---- kernel C: den[a*128+c] = sum_b S[a][b][c]; fuse ratio + reduction ----
__global__ __launch_bounds__(256) void reduce_kernel(const float* __restrict__ S,
                                                     const float* __restrict__ num,
                                                     float* __restrict__ accum) {
    const int a = blockIdx.x;
    const int t = threadIdx.x;
    const int c = t & 127, h = t >> 7;     // h splits the b-range in two
    const float* base = S + (size_t)a * (NTB * NTILE) + (size_t)h * 64 * NTILE + c;
    float s = 0.0f;
    #pragma unroll 8
    for (int b = 0; b < 64; b++) s += base[(size_t)b * NTILE];

    __shared__ float part[NTILE];
    __shared__ float wsum[4];
    if (h == 0) part[c] = s;
    __syncthreads();

    float r = 0.0f;
    if (h == 1) {
        const float E2 = 7.38905609893065f;  // exp(1/T)=exp(2): diagonal removal
        const float den = (part[c] + s) - E2;
        r = num[a * NTILE + c] / den;
    }
    #pragma unroll
    for (int o = 32; o > 0; o >>= 1) r += __shfl_xor(r, o, 64);
    if ((t & 63) == 0) wsum[t >> 6] = r;
    __syncthreads();
    if (t == 0) atomicAdd(accum, (wsum[0] + wsum[1]) + (wsum[2] + wsum[3]));
}

// ---- kernel D: final scalar ----------------------------------------------
__global__ void final_kernel(const float* __restrict__ accum, float* __restrict__ out) {
    out[0] = -logf(accum[0] / (float)NROWS);
}

extern "C" void kernel_launch(void* const* d_in, const int* in_sizes, int n_in,
                              void* d_out, int out_size, void* d_ws, size_t ws_size,
                              hipStream_t stream) {
    const float* x = (const float*)d_in[0];
    float* out = (float*)d_out;

    // ws layout: xnb [16384*64 bf16 = 2 MB] | num [16384 f32] | accum [1 f32]
    //          | S [128*128*128 f32 = 8 MB]
    __hip_bfloat16* xnb = (__hip_bfloat16*)d_ws;
    float* num = (float*)((char*)d_ws + (size_t)NROWS * KDIM * sizeof(__hip_bfloat16));
    float* accum = num + NROWS;
    float* S = accum + 1;

    normalize_kernel<<<NROWS / 4, 256, 0, stream>>>(x, xnb, accum);
    den_kernel<<<NPAIRS, 256, 0, stream>>>(xnb, S, num);
    reduce_kernel<<<NTB, 256, 0, stream>>>(S, num, accum);
    final_kernel<<<1, 1, 0, stream>>>(accum, out);
}